// Round 1
// baseline (18315.056 us; speedup 1.0000x reference)
//
#include <hip/hip_runtime.h>
#include <math.h>

// Problem dims
#define T_ 128
#define B_ 512
#define N_ 256
#define M_ 512
#define G_ 2048   // 4*M

// ---------------------------------------------------------------------------
// Generic tiled fp32 GEMM: C[r,c] = sum_k A(r,k)*W(c,k)  (+ optional 2nd pair)
// 64x64 tile, 256 threads (16x16), 4x4 micro-tile, K staged in LDS chunks of 16.
// MODE 0: C = acc + bias1[c] (+bias2[c])
// MODE 1: v = tanh(acc + bias1[c]) * vw[c]; row-sum atomically added into
//         lout[(r%512)*128 + (r/512)]   (the h_seq -> l reduction)
// ---------------------------------------------------------------------------
template<int MODE>
__global__ __launch_bounds__(256) void gemm_aw(
    const float* __restrict__ A1, int lda1,
    const float* __restrict__ W1, int ldw1, int K1,
    const float* __restrict__ A2, int lda2,
    const float* __restrict__ W2, int ldw2, int K2,
    const float* __restrict__ bias1, const float* __restrict__ bias2,
    float* __restrict__ C, int ldc,
    const float* __restrict__ vw, float* __restrict__ lout)
{
    __shared__ float As[16][68];
    __shared__ float Ws[16][68];
    __shared__ float rsum[64];

    const int tid = threadIdx.x;
    const int tx = tid & 15, ty = tid >> 4;
    const int row0 = blockIdx.y * 64;
    const int col0 = blockIdx.x * 64;
    const int li = tid >> 2;          // 0..63
    const int lk4 = (tid & 3) * 4;    // 0,4,8,12

    float acc[4][4];
#pragma unroll
    for (int r = 0; r < 4; r++)
#pragma unroll
        for (int c = 0; c < 4; c++) acc[r][c] = 0.f;

#pragma unroll 1
    for (int pass = 0; pass < 2; pass++) {
        const float* A = pass ? A2 : A1;
        const float* W = pass ? W2 : W1;
        const int lda = pass ? lda2 : lda1;
        const int ldw = pass ? ldw2 : ldw1;
        const int K  = pass ? K2  : K1;
#pragma unroll 1
        for (int kk = 0; kk < K; kk += 16) {
            float4 av = *(const float4*)&A[(size_t)(row0 + li) * lda + kk + lk4];
            float4 wv = *(const float4*)&W[(size_t)(col0 + li) * ldw + kk + lk4];
            __syncthreads();
            As[lk4 + 0][li] = av.x; As[lk4 + 1][li] = av.y;
            As[lk4 + 2][li] = av.z; As[lk4 + 3][li] = av.w;
            Ws[lk4 + 0][li] = wv.x; Ws[lk4 + 1][li] = wv.y;
            Ws[lk4 + 2][li] = wv.z; Ws[lk4 + 3][li] = wv.w;
            __syncthreads();
#pragma unroll
            for (int k = 0; k < 16; k++) {
                float4 a = *(const float4*)&As[k][ty * 4];
                float4 w = *(const float4*)&Ws[k][tx * 4];
                acc[0][0] += a.x * w.x; acc[0][1] += a.x * w.y;
                acc[0][2] += a.x * w.z; acc[0][3] += a.x * w.w;
                acc[1][0] += a.y * w.x; acc[1][1] += a.y * w.y;
                acc[1][2] += a.y * w.z; acc[1][3] += a.y * w.w;
                acc[2][0] += a.z * w.x; acc[2][1] += a.z * w.y;
                acc[2][2] += a.z * w.z; acc[2][3] += a.z * w.w;
                acc[3][0] += a.w * w.x; acc[3][1] += a.w * w.y;
                acc[3][2] += a.w * w.z; acc[3][3] += a.w * w.w;
            }
        }
    }

    if (MODE == 0) {
#pragma unroll
        for (int r = 0; r < 4; r++) {
            int gr = row0 + ty * 4 + r;
            int gc0 = col0 + tx * 4;
            float4 v;
            v.x = acc[r][0]; v.y = acc[r][1]; v.z = acc[r][2]; v.w = acc[r][3];
            if (bias1) { v.x += bias1[gc0]; v.y += bias1[gc0+1]; v.z += bias1[gc0+2]; v.w += bias1[gc0+3]; }
            if (bias2) { v.x += bias2[gc0]; v.y += bias2[gc0+1]; v.z += bias2[gc0+2]; v.w += bias2[gc0+3]; }
            *(float4*)&C[(size_t)gr * ldc + gc0] = v;
        }
    } else {
        // MODE 1: tanh + dot with vw, reduce per row, atomic into lout
        __syncthreads();
        if (tid < 64) rsum[tid] = 0.f;
        __syncthreads();
        float part[4] = {0.f, 0.f, 0.f, 0.f};
#pragma unroll
        for (int r = 0; r < 4; r++)
#pragma unroll
            for (int c = 0; c < 4; c++) {
                int gc = col0 + tx * 4 + c;
                float v = tanhf(acc[r][c] + bias1[gc]) * vw[gc];
                part[r] += v;
            }
#pragma unroll
        for (int r = 0; r < 4; r++)
            atomicAdd(&rsum[ty * 4 + r], part[r]);
        __syncthreads();
        if (tid < 64) {
            int gr = row0 + tid;          // gr = t*512 + b
            int b = gr & 511, t = gr >> 9;
            atomicAdd(&lout[b * 128 + t], rsum[tid]);
        }
    }
}

// ---------------------------------------------------------------------------
// Precompute Ue_x[b,s,n] = sum_t x[t,b,n]*Ue_w[s,t] + Ue_b[s], layout (b,s,n)
// block: (s-chunk of 32, b); 256 threads = n
// ---------------------------------------------------------------------------
__global__ __launch_bounds__(256) void ue_pre(
    const float* __restrict__ x, const float* __restrict__ Ue_w,
    const float* __restrict__ Ue_b, float* __restrict__ ue)
{
    const int b = blockIdx.y;
    const int s0 = blockIdx.x * 32;
    const int n = threadIdx.x;
    __shared__ float xs[32][256];
    __shared__ float uws[32][32];   // [s][t] chunk

    float acc[32];
#pragma unroll
    for (int i = 0; i < 32; i++) acc[i] = 0.f;

#pragma unroll 1
    for (int tc = 0; tc < 4; tc++) {
        __syncthreads();
#pragma unroll
        for (int tt = 0; tt < 32; tt++)
            xs[tt][n] = x[(size_t)(tc * 32 + tt) * (B_ * N_) + b * N_ + n];
#pragma unroll
        for (int q = 0; q < 4; q++) {
            int e = q * 256 + n;
            int s = e >> 5, tt = e & 31;
            uws[s][tt] = Ue_w[(s0 + s) * T_ + tc * 32 + tt];
        }
        __syncthreads();
        float xr[32];
#pragma unroll
        for (int tt = 0; tt < 32; tt++) xr[tt] = xs[tt][n];
#pragma unroll
        for (int s = 0; s < 32; s++) {
            float a = acc[s];
#pragma unroll
            for (int tt = 0; tt < 32; tt++) a += xr[tt] * uws[s][tt];
            acc[s] = a;
        }
    }
#pragma unroll
    for (int s = 0; s < 32; s++)
        ue[((size_t)b * T_ + s0 + s) * N_ + n] = acc[s] + Ue_b[s0 + s];
}

// ---------------------------------------------------------------------------
// Per-step attention: e[b,n] = sum_s tanh(we[b,s]+Ue_x[b,s,n])*ve[s];
// alpha = softmax_n(e); x_tilde = alpha * x_t.  block=b (512), 256 threads=n
// ---------------------------------------------------------------------------
__global__ __launch_bounds__(256) void attn_step(
    const float* __restrict__ ue, const float* __restrict__ webuf,
    const float* __restrict__ ve_w, const float* __restrict__ x_t,
    float* __restrict__ x_tilde)
{
    const int b = blockIdx.x;
    const int n = threadIdx.x;
    __shared__ float we_s[128];
    __shared__ float ve_s[128];
    __shared__ float red[256];

    if (n < 128) { we_s[n] = webuf[b * 128 + n]; ve_s[n] = ve_w[n]; }
    __syncthreads();

    const float* up = ue + (size_t)b * T_ * N_ + n;
    float acc = 0.f;
#pragma unroll 4
    for (int s = 0; s < 128; s++)
        acc += tanhf(we_s[s] + up[s * N_]) * ve_s[s];

    // softmax over n (256)
    red[n] = acc; __syncthreads();
    for (int off = 128; off > 0; off >>= 1) {
        if (n < off) red[n] = fmaxf(red[n], red[n + off]);
        __syncthreads();
    }
    float mx = red[0]; __syncthreads();
    float ex = expf(acc - mx);
    red[n] = ex; __syncthreads();
    for (int off = 128; off > 0; off >>= 1) {
        if (n < off) red[n] += red[n + off];
        __syncthreads();
    }
    float alpha = ex / red[0];
    x_tilde[b * N_ + n] = alpha * x_t[b * N_ + n];
}

// ---------------------------------------------------------------------------
// LSTM pointwise cell update. idx over B*M.
// ---------------------------------------------------------------------------
__global__ __launch_bounds__(256) void lstm_cell(
    const float* __restrict__ gates, float* __restrict__ c,
    float* __restrict__ hseq_t)
{
    const int idx = blockIdx.x * 256 + threadIdx.x;
    const int b = idx >> 9, m = idx & 511;
    const float* g = gates + (size_t)b * G_;
    float gi = g[m], gf = g[512 + m], gg = g[1024 + m], go = g[1536 + m];
    float si = 1.f / (1.f + expf(-gi));
    float sf = 1.f / (1.f + expf(-gf));
    float so = 1.f / (1.f + expf(-go));
    float cn = sf * c[idx] + si * tanhf(gg);
    c[idx] = cn;
    hseq_t[idx] = so * tanhf(cn);
}

// ---------------------------------------------------------------------------
// Final: beta = softmax_t(l[b,:]); ctx = sum_t beta*h_seq[t,b,:];
// logits = ctx.out_w + out_b. Writes both outputs. block=b, 512 threads=m
// ---------------------------------------------------------------------------
__global__ __launch_bounds__(512) void final_kernel(
    const float* __restrict__ lbuf, const float* __restrict__ hseq,
    const float* __restrict__ out_w, const float* __restrict__ out_b,
    float* __restrict__ out)
{
    const int b = blockIdx.x;
    const int tid = threadIdx.x;
    __shared__ float beta_s[128];
    __shared__ float red[512];

    float lv = (tid < 128) ? lbuf[b * 128 + tid] : -1e30f;
    red[tid] = lv; __syncthreads();
    for (int off = 256; off >= 1; off >>= 1) {
        if (tid < off) red[tid] = fmaxf(red[tid], red[tid + off]);
        __syncthreads();
    }
    float mx = red[0]; __syncthreads();
    float ex = (tid < 128) ? expf(lv - mx) : 0.f;
    red[tid] = ex; __syncthreads();
    for (int off = 256; off >= 1; off >>= 1) {
        if (tid < off) red[tid] += red[tid + off];
        __syncthreads();
    }
    float denom = red[0];
    if (tid < 128) {
        float bt = ex / denom;
        beta_s[tid] = bt;
        out[512 + b * 128 + tid] = bt;   // beta output
    }
    __syncthreads();

    float ctx = 0.f;
#pragma unroll 4
    for (int t = 0; t < 128; t++)
        ctx += beta_s[t] * hseq[(size_t)t * (B_ * M_) + b * M_ + tid];

    red[tid] = ctx * out_w[tid]; __syncthreads();
    for (int off = 256; off >= 1; off >>= 1) {
        if (tid < off) red[tid] += red[tid + off];
        __syncthreads();
    }
    if (tid == 0) out[b] = red[0] + out_b[0];   // logits output
}

// ---------------------------------------------------------------------------
extern "C" void kernel_launch(void* const* d_in, const int* in_sizes, int n_in,
                              void* d_out, int out_size, void* d_ws, size_t ws_size,
                              hipStream_t stream)
{
    const float* x    = (const float*)d_in[0];
    const float* h0   = (const float*)d_in[1];
    const float* c0   = (const float*)d_in[2];
    const float* Wih  = (const float*)d_in[3];
    const float* Whh  = (const float*)d_in[4];
    const float* b_ih = (const float*)d_in[5];
    const float* b_hh = (const float*)d_in[6];
    const float* We_w = (const float*)d_in[7];
    const float* We_b = (const float*)d_in[8];
    const float* Ue_w = (const float*)d_in[9];
    const float* Ue_b = (const float*)d_in[10];
    const float* ve_w = (const float*)d_in[11];
    // d_in[12] = ve_b : constant across n, cancels in softmax -> unused
    const float* Ud_w = (const float*)d_in[13];
    const float* Ud_b = (const float*)d_in[14];
    const float* vd_w = (const float*)d_in[15];
    // d_in[16] = vd_b : constant across t, cancels in softmax -> unused
    const float* out_w = (const float*)d_in[17];
    const float* out_b = (const float*)d_in[18];
    float* out = (float*)d_out;

    // workspace layout (floats)
    float* ws    = (float*)d_ws;
    float* ue    = ws;                       // 16,777,216  (B*T*N)
    float* hseq  = ue + 16777216;            // 33,554,432  (T*B*M)
    float* cbuf  = hseq + 33554432;          //    262,144  (B*M)
    float* webuf = cbuf + 262144;            //     65,536  (B*T)
    float* xt    = webuf + 65536;            //    131,072  (B*N)
    float* gates = xt + 131072;              //  1,048,576  (B*4M)
    float* lbuf  = gates + 1048576;          //     65,536  (B*T)

    hipMemcpyAsync(cbuf, c0, (size_t)B_ * M_ * 4, hipMemcpyDeviceToDevice, stream);
    hipMemsetAsync(lbuf, 0, (size_t)B_ * T_ * 4, stream);

    ue_pre<<<dim3(4, 512), 256, 0, stream>>>(x, Ue_w, Ue_b, ue);

    for (int t = 0; t < T_; t++) {
        const float* hprev = t ? (hseq + (size_t)(t - 1) * (B_ * M_)) : h0;
        // S1: we[b,s] = [h,c] @ We_w^T + We_b   (512 x 128, K=512+512)
        gemm_aw<0><<<dim3(2, 8), 256, 0, stream>>>(
            hprev, M_, We_w, 2 * M_, M_,
            cbuf,  M_, We_w + M_, 2 * M_, M_,
            We_b, nullptr, webuf, T_, nullptr, nullptr);
        // S2: attention + softmax + x_tilde
        attn_step<<<512, 256, 0, stream>>>(ue, webuf, ve_w,
                                           x + (size_t)t * (B_ * N_), xt);
        // S3a: gates = x_tilde@Wih^T + h@Whh^T + b_ih + b_hh  (512x2048, K=256+512)
        gemm_aw<0><<<dim3(32, 8), 256, 0, stream>>>(
            xt, N_, Wih, N_, N_,
            hprev, M_, Whh, M_, M_,
            b_ih, b_hh, gates, G_, nullptr, nullptr);
        // S3b: cell update -> c, h_seq[t]
        lstm_cell<<<1024, 256, 0, stream>>>(gates, cbuf,
                                            hseq + (size_t)t * (B_ * M_));
    }

    // P2: l[b,t] += sum_mm tanh(h_seq@Ud_w^T + Ud_b)*vd_w  (rows = T*B, cols = M)
    gemm_aw<1><<<dim3(8, 1024), 256, 0, stream>>>(
        hseq, M_, Ud_w, M_, M_,
        nullptr, 0, nullptr, 0, 0,
        Ud_b, nullptr, nullptr, 0, vd_w, lbuf);

    // P3: softmax over t, context, logits; writes d_out
    final_kernel<<<512, 512, 0, stream>>>(lbuf, hseq, out_w, out_b, out);
}

// Round 2
// 16026.144 us; speedup vs baseline: 1.1428x; 1.1428x over previous
//
#include <hip/hip_runtime.h>
#include <math.h>

// Problem dims
#define T_ 128
#define B_ 512
#define N_ 256
#define M_ 512
#define G_ 2048   // 4*M

// ---------------------------------------------------------------------------
// Prep: Wg[4m+g][k] = k<256 ? Wih[g*512+m][k] : Whh[g*512+m][k-256]
//       bg[4m+g]    = b_ih[g*512+m] + b_hh[g*512+m]
// Gate-interleaved so one 64-col GEMM tile = 16 complete (i,f,g,o) groups.
// ---------------------------------------------------------------------------
__global__ __launch_bounds__(256) void prep_wg(
    const float* __restrict__ Wih, const float* __restrict__ Whh,
    const float* __restrict__ bih, const float* __restrict__ bhh,
    float* __restrict__ Wg, float* __restrict__ bg)
{
    const int rp = blockIdx.x;          // 0..2047  (= 4*m + g)
    const int m = rp >> 2, g = rp & 3;
    const int row = g * 512 + m;
    for (int k = threadIdx.x; k < 768; k += 256)
        Wg[(size_t)rp * 768 + k] = (k < 256) ? Wih[(size_t)row * 256 + k]
                                             : Whh[(size_t)row * 512 + (k - 256)];
    if (threadIdx.x == 0) bg[rp] = bih[row] + bhh[row];
}

// ---------------------------------------------------------------------------
// S1: we[b,s] = [h,c] @ We_w^T + We_b.  Tile 64(b) x 16(s), grid (8,8)=64 blk.
// Register-prefetched K chunks of 16.
// ---------------------------------------------------------------------------
__global__ __launch_bounds__(256) void gemm_we(
    const float* __restrict__ h, const float* __restrict__ c,
    const float* __restrict__ We_w, const float* __restrict__ We_b,
    float* __restrict__ webuf)
{
    __shared__ float As[16][68];
    __shared__ float Ws[16][20];

    const int tid = threadIdx.x;
    const int tx = tid & 15, ty = tid >> 4;
    const int row0 = blockIdx.y * 64;   // b
    const int col0 = blockIdx.x * 16;   // s
    const int li = tid >> 2;            // 0..63
    const int lk4 = (tid & 3) * 4;
    const int wcol = tid >> 2;          // for W load (tid<64): 0..15
    const bool wload = tid < 64;

    float acc[4] = {0.f, 0.f, 0.f, 0.f};

#pragma unroll 1
    for (int pass = 0; pass < 2; pass++) {
        const float* A = pass ? c : h;
        const float* W = We_w + (pass ? 512 : 0);
        float4 av = *(const float4*)&A[(size_t)(row0 + li) * M_ + lk4];
        float4 wv = wload ? *(const float4*)&W[(size_t)(col0 + wcol) * 1024 + lk4]
                          : make_float4(0, 0, 0, 0);
#pragma unroll 1
        for (int kk = 0; kk < 512; kk += 16) {
            __syncthreads();
            As[lk4 + 0][li] = av.x; As[lk4 + 1][li] = av.y;
            As[lk4 + 2][li] = av.z; As[lk4 + 3][li] = av.w;
            if (wload) {
                Ws[lk4 + 0][wcol] = wv.x; Ws[lk4 + 1][wcol] = wv.y;
                Ws[lk4 + 2][wcol] = wv.z; Ws[lk4 + 3][wcol] = wv.w;
            }
            __syncthreads();
            if (kk + 16 < 512) {
                av = *(const float4*)&A[(size_t)(row0 + li) * M_ + kk + 16 + lk4];
                if (wload) wv = *(const float4*)&W[(size_t)(col0 + wcol) * 1024 + kk + 16 + lk4];
            }
#pragma unroll
            for (int k = 0; k < 16; k++) {
                float4 a = *(const float4*)&As[k][ty * 4];
                float w = Ws[k][tx];
                acc[0] += a.x * w; acc[1] += a.y * w;
                acc[2] += a.z * w; acc[3] += a.w * w;
            }
        }
    }
    const float bias = We_b[col0 + tx];
#pragma unroll
    for (int r = 0; r < 4; r++)
        webuf[(size_t)(row0 + ty * 4 + r) * T_ + col0 + tx] = acc[r] + bias;
}

// ---------------------------------------------------------------------------
// S2: e[b,n] = sum_s tanh(we[b,s]+Ue_x[b,s,n])*ve[s]; alpha=softmax_n(e);
// x_tilde = alpha * x_t.  block=b (512), 256 threads=n
// ---------------------------------------------------------------------------
__global__ __launch_bounds__(256) void attn_step(
    const float* __restrict__ ue, const float* __restrict__ webuf,
    const float* __restrict__ ve_w, const float* __restrict__ x_t,
    float* __restrict__ x_tilde)
{
    const int b = blockIdx.x;
    const int n = threadIdx.x;
    __shared__ float we_s[128];
    __shared__ float ve_s[128];
    __shared__ float red[256];

    if (n < 128) { we_s[n] = webuf[b * 128 + n]; ve_s[n] = ve_w[n]; }
    __syncthreads();

    const float* up = ue + (size_t)b * T_ * N_ + n;
    float acc = 0.f;
#pragma unroll 4
    for (int s = 0; s < 128; s++)
        acc += tanhf(we_s[s] + up[s * N_]) * ve_s[s];

    red[n] = acc; __syncthreads();
    for (int off = 128; off > 0; off >>= 1) {
        if (n < off) red[n] = fmaxf(red[n], red[n + off]);
        __syncthreads();
    }
    float mx = red[0]; __syncthreads();
    float ex = expf(acc - mx);
    red[n] = ex; __syncthreads();
    for (int off = 128; off > 0; off >>= 1) {
        if (n < off) red[n] += red[n + off];
        __syncthreads();
    }
    float alpha = ex / red[0];
    x_tilde[b * N_ + n] = alpha * x_t[b * N_ + n];
}

// ---------------------------------------------------------------------------
// S3: gates = x_tilde@Wih^T + h@Whh^T + biases (via interleaved Wg),
// fused LSTM cell epilogue -> writes c (in place) and h_seq[t].
// Tile 64(b) x 64(gate-cols) = 16 m-groups; grid (32,8)=256 blocks.
// ---------------------------------------------------------------------------
__global__ __launch_bounds__(256) void gemm_gates(
    const float* __restrict__ xt, const float* __restrict__ h,
    const float* __restrict__ Wg, const float* __restrict__ bg,
    float* __restrict__ c, float* __restrict__ hseq_t)
{
    __shared__ float As[16][68];
    __shared__ float Ws[16][68];

    const int tid = threadIdx.x;
    const int tx = tid & 15, ty = tid >> 4;
    const int row0 = blockIdx.y * 64;   // b
    const int col0 = blockIdx.x * 64;   // gate col (4m+g)
    const int li = tid >> 2;
    const int lk4 = (tid & 3) * 4;

    float acc[4][4];
#pragma unroll
    for (int r = 0; r < 4; r++)
#pragma unroll
        for (int cc = 0; cc < 4; cc++) acc[r][cc] = 0.f;

#pragma unroll 1
    for (int pass = 0; pass < 2; pass++) {
        const float* A = pass ? h : xt;
        const int lda = pass ? M_ : N_;
        const int K = pass ? 512 : 256;
        const float* W = Wg + (pass ? 256 : 0);
        float4 av = *(const float4*)&A[(size_t)(row0 + li) * lda + lk4];
        float4 wv = *(const float4*)&W[(size_t)(col0 + li) * 768 + lk4];
#pragma unroll 1
        for (int kk = 0; kk < K; kk += 16) {
            __syncthreads();
            As[lk4 + 0][li] = av.x; As[lk4 + 1][li] = av.y;
            As[lk4 + 2][li] = av.z; As[lk4 + 3][li] = av.w;
            Ws[lk4 + 0][li] = wv.x; Ws[lk4 + 1][li] = wv.y;
            Ws[lk4 + 2][li] = wv.z; Ws[lk4 + 3][li] = wv.w;
            __syncthreads();
            if (kk + 16 < K) {
                av = *(const float4*)&A[(size_t)(row0 + li) * lda + kk + 16 + lk4];
                wv = *(const float4*)&W[(size_t)(col0 + li) * 768 + kk + 16 + lk4];
            }
#pragma unroll
            for (int k = 0; k < 16; k++) {
                float4 a = *(const float4*)&As[k][ty * 4];
                float4 w = *(const float4*)&Ws[k][tx * 4];
                acc[0][0] += a.x * w.x; acc[0][1] += a.x * w.y;
                acc[0][2] += a.x * w.z; acc[0][3] += a.x * w.w;
                acc[1][0] += a.y * w.x; acc[1][1] += a.y * w.y;
                acc[1][2] += a.y * w.z; acc[1][3] += a.y * w.w;
                acc[2][0] += a.z * w.x; acc[2][1] += a.z * w.y;
                acc[2][2] += a.z * w.z; acc[2][3] += a.z * w.w;
                acc[3][0] += a.w * w.x; acc[3][1] += a.w * w.y;
                acc[3][2] += a.w * w.z; acc[3][3] += a.w * w.w;
            }
        }
    }

    // Fused cell: thread owns m = col0/4 + tx, gates i,f,g,o = acc[r][0..3]
    const int m = (col0 >> 2) + tx;
    const float bi = bg[col0 + tx * 4 + 0];
    const float bf = bg[col0 + tx * 4 + 1];
    const float bgg = bg[col0 + tx * 4 + 2];
    const float bo = bg[col0 + tx * 4 + 3];
#pragma unroll
    for (int r = 0; r < 4; r++) {
        const int b = row0 + ty * 4 + r;
        const int idx = b * M_ + m;
        float gi = acc[r][0] + bi;
        float gf = acc[r][1] + bf;
        float gc = acc[r][2] + bgg;
        float go = acc[r][3] + bo;
        float si = 1.f / (1.f + expf(-gi));
        float sf = 1.f / (1.f + expf(-gf));
        float so = 1.f / (1.f + expf(-go));
        float cn = sf * c[idx] + si * tanhf(gc);
        c[idx] = cn;
        hseq_t[idx] = so * tanhf(cn);
    }
}

// ---------------------------------------------------------------------------
// Precompute Ue_x[b,s,n] = sum_t x[t,b,n]*Ue_w[s,t] + Ue_b[s], layout (b,s,n)
// ---------------------------------------------------------------------------
__global__ __launch_bounds__(256) void ue_pre(
    const float* __restrict__ x, const float* __restrict__ Ue_w,
    const float* __restrict__ Ue_b, float* __restrict__ ue)
{
    const int b = blockIdx.y;
    const int s0 = blockIdx.x * 32;
    const int n = threadIdx.x;
    __shared__ float xs[32][256];
    __shared__ float uws[32][32];

    float acc[32];
#pragma unroll
    for (int i = 0; i < 32; i++) acc[i] = 0.f;

#pragma unroll 1
    for (int tc = 0; tc < 4; tc++) {
        __syncthreads();
#pragma unroll
        for (int tt = 0; tt < 32; tt++)
            xs[tt][n] = x[(size_t)(tc * 32 + tt) * (B_ * N_) + b * N_ + n];
#pragma unroll
        for (int q = 0; q < 4; q++) {
            int e = q * 256 + n;
            int s = e >> 5, tt = e & 31;
            uws[s][tt] = Ue_w[(s0 + s) * T_ + tc * 32 + tt];
        }
        __syncthreads();
        float xr[32];
#pragma unroll
        for (int tt = 0; tt < 32; tt++) xr[tt] = xs[tt][n];
#pragma unroll
        for (int s = 0; s < 32; s++) {
            float a = acc[s];
#pragma unroll
            for (int tt = 0; tt < 32; tt++) a += xr[tt] * uws[s][tt];
            acc[s] = a;
        }
    }
#pragma unroll
    for (int s = 0; s < 32; s++)
        ue[((size_t)b * T_ + s0 + s) * N_ + n] = acc[s] + Ue_b[s0 + s];
}

// ---------------------------------------------------------------------------
// Post: l[b,t] += sum_m tanh(h_seq@Ud_w^T + Ud_b)*vd_w   (rows=T*B, cols=M)
// ---------------------------------------------------------------------------
__global__ __launch_bounds__(256) void gemm_l(
    const float* __restrict__ A1,
    const float* __restrict__ W1,
    const float* __restrict__ bias1,
    const float* __restrict__ vw, float* __restrict__ lout)
{
    __shared__ float As[16][68];
    __shared__ float Ws[16][68];
    __shared__ float rsum[64];

    const int tid = threadIdx.x;
    const int tx = tid & 15, ty = tid >> 4;
    const int row0 = blockIdx.y * 64;
    const int col0 = blockIdx.x * 64;
    const int li = tid >> 2;
    const int lk4 = (tid & 3) * 4;

    float acc[4][4];
#pragma unroll
    for (int r = 0; r < 4; r++)
#pragma unroll
        for (int cc = 0; cc < 4; cc++) acc[r][cc] = 0.f;

    float4 av = *(const float4*)&A1[(size_t)(row0 + li) * M_ + lk4];
    float4 wv = *(const float4*)&W1[(size_t)(col0 + li) * M_ + lk4];
#pragma unroll 1
    for (int kk = 0; kk < 512; kk += 16) {
        __syncthreads();
        As[lk4 + 0][li] = av.x; As[lk4 + 1][li] = av.y;
        As[lk4 + 2][li] = av.z; As[lk4 + 3][li] = av.w;
        Ws[lk4 + 0][li] = wv.x; Ws[lk4 + 1][li] = wv.y;
        Ws[lk4 + 2][li] = wv.z; Ws[lk4 + 3][li] = wv.w;
        __syncthreads();
        if (kk + 16 < 512) {
            av = *(const float4*)&A1[(size_t)(row0 + li) * M_ + kk + 16 + lk4];
            wv = *(const float4*)&W1[(size_t)(col0 + li) * M_ + kk + 16 + lk4];
        }
#pragma unroll
        for (int k = 0; k < 16; k++) {
            float4 a = *(const float4*)&As[k][ty * 4];
            float4 w = *(const float4*)&Ws[k][tx * 4];
            acc[0][0] += a.x * w.x; acc[0][1] += a.x * w.y;
            acc[0][2] += a.x * w.z; acc[0][3] += a.x * w.w;
            acc[1][0] += a.y * w.x; acc[1][1] += a.y * w.y;
            acc[1][2] += a.y * w.z; acc[1][3] += a.y * w.w;
            acc[2][0] += a.z * w.x; acc[2][1] += a.z * w.y;
            acc[2][2] += a.z * w.z; acc[2][3] += a.z * w.w;
            acc[3][0] += a.w * w.x; acc[3][1] += a.w * w.y;
            acc[3][2] += a.w * w.z; acc[3][3] += a.w * w.w;
        }
    }

    __syncthreads();
    if (tid < 64) rsum[tid] = 0.f;
    __syncthreads();
    float part[4] = {0.f, 0.f, 0.f, 0.f};
#pragma unroll
    for (int r = 0; r < 4; r++)
#pragma unroll
        for (int cc = 0; cc < 4; cc++) {
            int gc = col0 + tx * 4 + cc;
            part[r] += tanhf(acc[r][cc] + bias1[gc]) * vw[gc];
        }
#pragma unroll
    for (int r = 0; r < 4; r++)
        atomicAdd(&rsum[ty * 4 + r], part[r]);
    __syncthreads();
    if (tid < 64) {
        int gr = row0 + tid;          // gr = t*512 + b
        int b = gr & 511, t = gr >> 9;
        atomicAdd(&lout[b * 128 + t], rsum[tid]);
    }
}

// ---------------------------------------------------------------------------
// Final: beta = softmax_t(l); ctx = sum_t beta*h_seq; logits = ctx.out_w+out_b
// ---------------------------------------------------------------------------
__global__ __launch_bounds__(512) void final_kernel(
    const float* __restrict__ lbuf, const float* __restrict__ hseq,
    const float* __restrict__ out_w, const float* __restrict__ out_b,
    float* __restrict__ out)
{
    const int b = blockIdx.x;
    const int tid = threadIdx.x;
    __shared__ float beta_s[128];
    __shared__ float red[512];

    float lv = (tid < 128) ? lbuf[b * 128 + tid] : -1e30f;
    red[tid] = lv; __syncthreads();
    for (int off = 256; off >= 1; off >>= 1) {
        if (tid < off) red[tid] = fmaxf(red[tid], red[tid + off]);
        __syncthreads();
    }
    float mx = red[0]; __syncthreads();
    float ex = (tid < 128) ? expf(lv - mx) : 0.f;
    red[tid] = ex; __syncthreads();
    for (int off = 256; off >= 1; off >>= 1) {
        if (tid < off) red[tid] += red[tid + off];
        __syncthreads();
    }
    float denom = red[0];
    if (tid < 128) {
        float bt = ex / denom;
        beta_s[tid] = bt;
        out[512 + b * 128 + tid] = bt;
    }
    __syncthreads();

    float ctx = 0.f;
#pragma unroll 4
    for (int t = 0; t < 128; t++)
        ctx += beta_s[t] * hseq[(size_t)t * (B_ * M_) + b * M_ + tid];

    red[tid] = ctx * out_w[tid]; __syncthreads();
    for (int off = 256; off >= 1; off >>= 1) {
        if (tid < off) red[tid] += red[tid + off];
        __syncthreads();
    }
    if (tid == 0) out[b] = red[0] + out_b[0];
}

// ---------------------------------------------------------------------------
extern "C" void kernel_launch(void* const* d_in, const int* in_sizes, int n_in,
                              void* d_out, int out_size, void* d_ws, size_t ws_size,
                              hipStream_t stream)
{
    const float* x    = (const float*)d_in[0];
    const float* h0   = (const float*)d_in[1];
    const float* c0   = (const float*)d_in[2];
    const float* Wih  = (const float*)d_in[3];
    const float* Whh  = (const float*)d_in[4];
    const float* b_ih = (const float*)d_in[5];
    const float* b_hh = (const float*)d_in[6];
    const float* We_w = (const float*)d_in[7];
    const float* We_b = (const float*)d_in[8];
    const float* Ue_w = (const float*)d_in[9];
    const float* Ue_b = (const float*)d_in[10];
    const float* ve_w = (const float*)d_in[11];
    const float* Ud_w = (const float*)d_in[13];
    const float* Ud_b = (const float*)d_in[14];
    const float* vd_w = (const float*)d_in[15];
    const float* out_w = (const float*)d_in[17];
    const float* out_b = (const float*)d_in[18];
    float* out = (float*)d_out;

    // workspace layout (floats)
    float* ws    = (float*)d_ws;
    float* ue    = ws;                       // 16,777,216  (B*T*N)
    float* hseq  = ue + 16777216;            // 33,554,432  (T*B*M)
    float* cbuf  = hseq + 33554432;          //    262,144  (B*M)
    float* webuf = cbuf + 262144;            //     65,536  (B*T)
    float* xt    = webuf + 65536;            //    131,072  (B*N)
    float* lbuf  = xt + 131072;              //     65,536  (B*T)
    float* Wg    = lbuf + 65536;             //  1,572,864  (2048*768)
    float* bgv   = Wg + 1572864;             //      2,048

    hipMemcpyAsync(cbuf, c0, (size_t)B_ * M_ * 4, hipMemcpyDeviceToDevice, stream);
    hipMemsetAsync(lbuf, 0, (size_t)B_ * T_ * 4, stream);

    prep_wg<<<2048, 256, 0, stream>>>(Wih, Whh, b_ih, b_hh, Wg, bgv);
    ue_pre<<<dim3(4, 512), 256, 0, stream>>>(x, Ue_w, Ue_b, ue);

    for (int t = 0; t < T_; t++) {
        const float* hprev = t ? (hseq + (size_t)(t - 1) * (B_ * M_)) : h0;
        gemm_we<<<dim3(8, 8), 256, 0, stream>>>(hprev, cbuf, We_w, We_b, webuf);
        attn_step<<<512, 256, 0, stream>>>(ue, webuf, ve_w,
                                           x + (size_t)t * (B_ * N_), xt);
        gemm_gates<<<dim3(32, 8), 256, 0, stream>>>(
            xt, hprev, Wg, bgv, cbuf, hseq + (size_t)t * (B_ * M_));
    }

    gemm_l<<<dim3(8, 1024), 256, 0, stream>>>(hseq, Ud_w, Ud_b, vd_w, lbuf);
    final_kernel<<<512, 512, 0, stream>>>(lbuf, hseq, out_w, out_b, out);
}